// Round 2
// baseline (680.958 us; speedup 1.0000x reference)
//
#include <hip/hip_runtime.h>
#include <hip/hip_bf16.h>

#define D 512
#define L_LAYERS 2
#define BATCH 8
#define TT 2048
#define N3 1536   // 3*D
#define REC 4096  // BATCH*D

typedef __attribute__((ext_vector_type(8))) short short8;
typedef __attribute__((ext_vector_type(4))) float floatx4;

#if __has_builtin(__builtin_amdgcn_exp2f)
#define EXP2F(x) __builtin_amdgcn_exp2f(x)
#else
#define EXP2F(x) exp2f(x)
#endif
#if __has_builtin(__builtin_amdgcn_rcpf)
#define RCPF(x) __builtin_amdgcn_rcpf(x)
#else
#define RCPF(x) (1.0f / (x))
#endif

__device__ __forceinline__ unsigned short f2bf(float f) {
  unsigned u = __builtin_bit_cast(unsigned, f);
  u += 0x7FFFu + ((u >> 16) & 1u);
  return (unsigned short)(u >> 16);
}

// ---- embedding gather: xa[(t*B+b)*D + d] = bf16(emb[ids[b][t]][d])
__global__ __launch_bounds__(128) void embed_kernel(const int* __restrict__ ids,
                                                    const float* __restrict__ emb,
                                                    unsigned short* __restrict__ xa) {
  int bt = blockIdx.x;          // b*T + t
  int b = bt >> 11;
  int t = bt & 2047;
  int id = ids[bt];
  int d = threadIdx.x << 2;
  const float4 v = *(const float4*)(emb + (size_t)id * D + d);
  ushort4 w;
  w.x = f2bf(v.x); w.y = f2bf(v.y); w.z = f2bf(v.z); w.w = f2bf(v.w);
  *(ushort4*)(xa + ((size_t)t * BATCH + b) * D + d) = w;
}

// ---- W transpose + convert: Wt[l][n][k] = bf16(Ws[l][k][n])
__global__ __launch_bounds__(256) void wconv_kernel(const float* __restrict__ Ws,
                                                    unsigned short* __restrict__ Wt) {
  int idx = blockIdx.x * 256 + threadIdx.x;
  if (idx >= L_LAYERS * D * N3) return;
  int n = idx % N3;
  int k = (idx / N3) % D;
  int l = idx / (N3 * D);
  Wt[((size_t)l * N3 + n) * D + k] = f2bf(Ws[idx]);
}

// ---- per-batch valid length (mask is monotone)
__global__ void len_kernel(const void* __restrict__ maskp, int* __restrict__ lenb) {
  int b = threadIdx.x;
  if (b >= BATCH) return;
  int w0 = *(const int*)maskp;
  int mode = (w0 == 1) ? 0 : ((w0 == 0x01010101) ? 1 : 2);  // i32 / u8 / f32
  int lo = 0, hi = TT;
  while (lo < hi) {
    int mid = (lo + hi) >> 1;
    int idx = b * TT + mid;
    bool mm = (mode == 0) ? (((const int*)maskp)[idx] != 0)
            : (mode == 1) ? (((const unsigned char*)maskp)[idx] != 0)
                          : (((const float*)maskp)[idx] != 0.f);
    if (mm) lo = mid + 1; else hi = mid;
  }
  lenb[b] = lo;
}

// ---- NT bf16 MFMA GEMM. Outputs packed as:
//   Ua[t*REC+rec] u32 = u0 | u1<<16   (rec = b*512+d, m = t*8+b)
//   Ub[t*REC+rec] u32 = u2 | x<<16
// Block swizzle: each XCD (blockIdx&7) owns 16 bm-tiles; bn iterates fastest
// within an XCD so the A-tile is read from HBM once and reused 12x from L2.
__global__ __launch_bounds__(256) void gemm_kernel(const unsigned short* __restrict__ A,
                                                   const unsigned short* __restrict__ Bt,
                                                   unsigned short* __restrict__ Ua16,
                                                   unsigned short* __restrict__ Ub16) {
  constexpr int K = D;
  __shared__ __align__(16) unsigned short As[128 * 32];
  __shared__ __align__(16) unsigned short Bs[128 * 32];
  int tid = threadIdx.x;
  int lane = tid & 63;
  int wave = tid >> 6;
  int bi = blockIdx.x;
  int xcd = bi & 7;
  int jj = bi >> 3;              // 0..191
  int bm = xcd * 16 + jj / 12;   // 128 M-tiles, 16 per XCD
  int bn = jj % 12;              // 12 N-tiles, fastest within XCD
  int m0 = bm * 128, n0 = bn * 128;
  int wm = (wave & 1) * 64, wn = (wave >> 1) * 64;
  int q = lane >> 4, r16 = lane & 15;
  floatx4 acc[4][4] = {};

  for (int k0 = 0; k0 < K; k0 += 32) {
#pragma unroll
    for (int i = 0; i < 2; ++i) {
      int chunk = tid + i * 256;
      int row = chunk >> 2;
      int off = (chunk & 3) * 8;
      __builtin_amdgcn_global_load_lds(
          (const __attribute__((address_space(1))) unsigned int*)(A + (size_t)(m0 + row) * K + k0 + off),
          (__attribute__((address_space(3))) unsigned int*)(As + chunk * 8), 16, 0, 0);
      __builtin_amdgcn_global_load_lds(
          (const __attribute__((address_space(1))) unsigned int*)(Bt + (size_t)(n0 + row) * K + k0 + off),
          (__attribute__((address_space(3))) unsigned int*)(Bs + chunk * 8), 16, 0, 0);
    }
    __syncthreads();
    short8 af[4], bfr[4];
#pragma unroll
    for (int i = 0; i < 4; ++i) {
      af[i]  = *(const short8*)&As[(wm + i * 16 + r16) * 32 + q * 8];
      bfr[i] = *(const short8*)&Bs[(wn + i * 16 + r16) * 32 + q * 8];
    }
#pragma unroll
    for (int mi = 0; mi < 4; ++mi)
#pragma unroll
      for (int ni = 0; ni < 4; ++ni)
        acc[mi][ni] = __builtin_amdgcn_mfma_f32_16x16x32_bf16(af[mi], bfr[ni], acc[mi][ni], 0, 0, 0);
    __syncthreads();
  }
  // epilogue: C/D layout col=lane&15, row=(lane>>4)*4+reg (verified m89/m91)
  int slotu = n0 >> 9;  // uniform per block: 0..3->u0, 4..7->u1, 8..11->u2
#pragma unroll
  for (int mi = 0; mi < 4; ++mi)
#pragma unroll
    for (int ni = 0; ni < 4; ++ni) {
      int n = n0 + wn + ni * 16 + r16;
      int dcol = n & 511;
#pragma unroll
      for (int i = 0; i < 4; ++i) {
        int m = m0 + wm + mi * 16 + q * 4 + i;
        size_t rec = (size_t)m * D + dcol;
        unsigned short v = f2bf(acc[mi][ni][i]);
        if (slotu == 0)      { Ua16[rec * 2] = v; Ub16[rec * 2 + 1] = A[rec]; }
        else if (slotu == 1) { Ua16[rec * 2 + 1] = v; }
        else                 { Ub16[rec * 2] = v; }
      }
    }
}

// ---- Fused serial chain + h epilogue. 64 blocks x 64 threads (1 wave/block).
// Per step (all in-register, no c round-trip through memory):
//   f  = sigm(u1 + vf*c + bf)          [on the recurrence critical path]
//   cn = u0 + f*(c - u0)
//   r  = sigm(u2 + vr*c + br)          [off-chain: uses c_{t-1}, overlaps f-chain]
//   h  = r*(tanh(cn) - x) + x          [off-chain: doesn't feed recurrence]
// The h work (4 extra trans + ~12 VALU) fills the in-order wave's stall
// shadows under the exp/rcp dependent chain. Replaces cchain+hpost, removing
// the 33.5MB c-store and 67MB c-reload per layer.
// 16-step chunks, register double-buffered (static indexing only, rule #20);
// in-flight vmem <= 32 loads + 16 stores stays inside the 6-bit vmcnt limit.
template <bool LAST>
__global__ __launch_bounds__(64) void fused_chain_kernel(const unsigned* __restrict__ Ua,
                                                         const unsigned* __restrict__ Ub,
                                                         const float* __restrict__ vsl,
                                                         const float* __restrict__ bsl,
                                                         const int* __restrict__ lenb,
                                                         unsigned short* __restrict__ Hout,
                                                         float* __restrict__ Out) {
  int tid = threadIdx.x;
  int ch = blockIdx.x * 64 + tid;
  int b = ch >> 9;              // uniform per block (64-ch blocks never straddle b)
  int d = ch & 511;
  int len = lenb[b];
  const float NL2E = -1.4426950408889634f;
  const float L2E2 = 2.8853900817779268f;
  float vfe = NL2E * vsl[d];
  float cbf = NL2E * bsl[d];
  float vre = NL2E * vsl[D + d];
  float cbr = NL2E * bsl[D + d];
  const unsigned* pa = Ua + ch;
  const unsigned* pb = Ub + ch;
  unsigned short* ph = Hout + ch;                      // stride REC (ushort), coalesced
  float* po = Out + (size_t)b * TT * D + d;            // stride D (f32), coalesced
  int nact = (len + 15) >> 4;   // 64..128 chunks of 16 steps

  unsigned aA[16], bA[16], aB[16], bB[16];

#define PLOAD(k, ua, ub)                                    \
  _Pragma("unroll") for (int j = 0; j < 16; ++j) {          \
    ua[j] = pa[(size_t)((k) * 16 + j) * REC];               \
    ub[j] = pb[(size_t)((k) * 16 + j) * REC];               \
  }

#define CCOMP(k, ua, ub)                                    \
  _Pragma("unroll") for (int j = 0; j < 16; ++j) {          \
    unsigned la = ua[j], lb = ub[j];                        \
    float u0 = __builtin_bit_cast(float, la << 16);         \
    float u1f = __builtin_bit_cast(float, la & 0xFFFF0000u);\
    float u2f = __builtin_bit_cast(float, lb << 16);        \
    float xf = __builtin_bit_cast(float, lb & 0xFFFF0000u); \
    float k1 = fmaf(u1f, NL2E, cbf);                        \
    float a2 = fmaf(vfe, c, k1);                            \
    float e = EXP2F(a2);                                    \
    float inv = RCPF(e + 1.f);                              \
    float cn = fmaf(c - u0, inv, u0);                       \
    float k2 = fmaf(u2f, NL2E, cbr);                        \
    float a2r = fmaf(vre, c, k2);                           \
    float er = EXP2F(a2r);                                  \
    float r = RCPF(er + 1.f);                               \
    float et = EXP2F(cn * L2E2);                            \
    float th = fmaf(-2.f, RCPF(et + 1.f), 1.f);             \
    float hv = fmaf(r, th - xf, xf);                        \
    int t = (k) * 16 + j;                                   \
    hv = (t < len) ? hv : 0.f;                              \
    c = cn;                                                 \
    if (LAST) po[(size_t)t * D] = hv;                       \
    else      ph[(size_t)t * REC] = f2bf(hv);               \
  }

  PLOAD(0, aA, bA);
  float c = 0.f;
  int k = 0;
  for (;;) {
    if (k + 1 < nact) PLOAD(k + 1, aB, bB);
    CCOMP(k, aA, bA);
    if (++k >= nact) break;
    if (k + 1 < nact) PLOAD(k + 1, aA, bA);
    CCOMP(k, aB, bB);
    if (++k >= nact) break;
  }
#undef PLOAD
#undef CCOMP

  // tail: t >= nact*16 is all-pad -> h = 0 (next layer's x / final out)
#pragma unroll 4
  for (int t = nact * 16; t < TT; ++t) {
    if (LAST) po[(size_t)t * D] = 0.f;
    else      ph[(size_t)t * REC] = 0;
  }
}

extern "C" void kernel_launch(void* const* d_in, const int* in_sizes, int n_in,
                              void* d_out, int out_size, void* d_ws, size_t ws_size,
                              hipStream_t stream) {
  const int* ids = (const int*)d_in[0];
  const void* mask = d_in[1];
  const float* emb = (const float*)d_in[2];
  const float* Ws = (const float*)d_in[3];
  const float* vs = (const float*)d_in[4];
  const float* bs = (const float*)d_in[5];
  float* out = (float*)d_out;

  char* ws = (char*)d_ws;
  unsigned short* Ua = (unsigned short*)ws;                   // 33.5 MB (u0|u1 per rec)
  unsigned short* Ub = Ua + (size_t)TT * REC * 2;             // 33.5 MB (u2|x per rec)
  unsigned short* xa = Ub + (size_t)TT * REC * 2;             // 16.8 MB
  unsigned short* xb = xa + (size_t)TT * BATCH * D;           // 16.8 MB
  unsigned short* Wt = xb + (size_t)TT * BATCH * D;           // 3.1 MB
  int* lenb = (int*)(Wt + (size_t)L_LAYERS * D * N3);

  embed_kernel<<<BATCH * TT, 128, 0, stream>>>(ids, emb, xa);
  wconv_kernel<<<(L_LAYERS * D * N3 + 255) / 256, 256, 0, stream>>>(Ws, Wt);
  len_kernel<<<1, 64, 0, stream>>>(mask, lenb);

  // layer 0
  gemm_kernel<<<128 * 12, 256, 0, stream>>>(xa, Wt, Ua, Ub);
  fused_chain_kernel<false><<<64, 64, 0, stream>>>((const unsigned*)Ua, (const unsigned*)Ub,
                                                   vs, bs, lenb, xb, nullptr);
  // layer 1
  gemm_kernel<<<128 * 12, 256, 0, stream>>>(xb, Wt + (size_t)N3 * D, Ua, Ub);
  fused_chain_kernel<true><<<64, 64, 0, stream>>>((const unsigned*)Ua, (const unsigned*)Ub,
                                                  vs + 2 * D, bs + 2 * D, lenb, nullptr, out);
}

// Round 3
// 484.659 us; speedup vs baseline: 1.4050x; 1.4050x over previous
//
#include <hip/hip_runtime.h>
#include <hip/hip_bf16.h>

#define D 512
#define L_LAYERS 2
#define BATCH 8
#define TT 2048
#define N3 1536   // 3*D
#define REC 4096  // BATCH*D

typedef __attribute__((ext_vector_type(8))) short short8;
typedef __attribute__((ext_vector_type(4))) float floatx4;

#if __has_builtin(__builtin_amdgcn_exp2f)
#define EXP2F(x) __builtin_amdgcn_exp2f(x)
#else
#define EXP2F(x) exp2f(x)
#endif
#if __has_builtin(__builtin_amdgcn_rcpf)
#define RCPF(x) __builtin_amdgcn_rcpf(x)
#else
#define RCPF(x) (1.0f / (x))
#endif

__device__ __forceinline__ unsigned short f2bf(float f) {
  unsigned u = __builtin_bit_cast(unsigned, f);
  u += 0x7FFFu + ((u >> 16) & 1u);
  return (unsigned short)(u >> 16);
}

// ---- embedding gather: xa[(t*B+b)*D + d] = bf16(emb[ids[b][t]][d])
__global__ __launch_bounds__(128) void embed_kernel(const int* __restrict__ ids,
                                                    const float* __restrict__ emb,
                                                    unsigned short* __restrict__ xa) {
  int bt = blockIdx.x;          // b*T + t
  int b = bt >> 11;
  int t = bt & 2047;
  int id = ids[bt];
  int d = threadIdx.x << 2;
  const float4 v = *(const float4*)(emb + (size_t)id * D + d);
  ushort4 w;
  w.x = f2bf(v.x); w.y = f2bf(v.y); w.z = f2bf(v.z); w.w = f2bf(v.w);
  *(ushort4*)(xa + ((size_t)t * BATCH + b) * D + d) = w;
}

// ---- W transpose + convert: Wt[l][n][k] = bf16(Ws[l][k][n])
__global__ __launch_bounds__(256) void wconv_kernel(const float* __restrict__ Ws,
                                                    unsigned short* __restrict__ Wt) {
  int idx = blockIdx.x * 256 + threadIdx.x;
  if (idx >= L_LAYERS * D * N3) return;
  int n = idx % N3;
  int k = (idx / N3) % D;
  int l = idx / (N3 * D);
  Wt[((size_t)l * N3 + n) * D + k] = f2bf(Ws[idx]);
}

// ---- per-batch valid length (mask is monotone)
__global__ void len_kernel(const void* __restrict__ maskp, int* __restrict__ lenb) {
  int b = threadIdx.x;
  if (b >= BATCH) return;
  int w0 = *(const int*)maskp;
  int mode = (w0 == 1) ? 0 : ((w0 == 0x01010101) ? 1 : 2);  // i32 / u8 / f32
  int lo = 0, hi = TT;
  while (lo < hi) {
    int mid = (lo + hi) >> 1;
    int idx = b * TT + mid;
    bool mm = (mode == 0) ? (((const int*)maskp)[idx] != 0)
            : (mode == 1) ? (((const unsigned char*)maskp)[idx] != 0)
                          : (((const float*)maskp)[idx] != 0.f);
    if (mm) lo = mid + 1; else hi = mid;
  }
  lenb[b] = lo;
}

// ---- 3-plane NT bf16 MFMA GEMM. One block computes a 128(m) x 128(dcol)
// output patch for ALL THREE planes (n = dcol, dcol+512, dcol+1024), so each
// lane owns u0,u1,u2 of the same (m,dcol) and the epilogue writes packed
// full dwords:
//   Ua[rec] = u0 | u1<<16,  Ub[rec] = u2 | x<<16   (rec = m*512+dcol, m=t*8+b)
// Bs columns are interleaved per-16 (plane p = (c>>4)%3) so a wave's 96-col
// slice contains all 3 planes of its 32 dcols.
// 512 threads / 8 waves: wave covers 64 m x 96 c -> acc[4][6].
// XCD swizzle: 4 dcol-blocks of the same bm share the A-panel in L2.
__global__ __launch_bounds__(512) void gemm_kernel(const unsigned short* __restrict__ A,
                                                   const unsigned short* __restrict__ Bt,
                                                   unsigned* __restrict__ Ua32,
                                                   unsigned* __restrict__ Ub32) {
  constexpr int K = D;
  __shared__ __align__(16) unsigned short As[128 * 32];   // 8 KB
  __shared__ __align__(16) unsigned short Bs[384 * 32];   // 24 KB
  int tid = threadIdx.x;
  int lane = tid & 63;
  int wave = tid >> 6;           // 0..7
  int bi = blockIdx.x;
  int xcd = bi & 7;
  int j = bi >> 3;               // 0..63
  int bm = xcd * 16 + (j >> 2);  // 0..127
  int dc0 = (j & 3) * 128;
  int m0 = bm * 128;
  int wm = (wave & 1) * 64;
  int w2 = wave >> 1;            // 0..3
  int q = lane >> 4, r16 = lane & 15;

  // staging geometry: each thread stages one 16B slot per tile
  int arow = tid >> 2;           // 0..127
  int aoff = (tid & 3) * 8;      // ushort offset within 32-col row
  int nsrc[3];
#pragma unroll
  for (int i = 0; i < 3; ++i) {
    int c = arow + i * 128;      // Bs column 0..383
    int g = c >> 4;              // 0..23
    int p = g % 3;
    int dcol = (g / 3) * 16 + (c & 15);
    nsrc[i] = dc0 + dcol + p * 512;
  }
  const unsigned short* asrc = A + (size_t)(m0 + arow) * K + aoff;

  floatx4 acc[4][6] = {};

  for (int k0 = 0; k0 < K; k0 += 32) {
    __builtin_amdgcn_global_load_lds(
        (const __attribute__((address_space(1))) unsigned int*)(asrc + k0),
        (__attribute__((address_space(3))) unsigned int*)(As + tid * 8), 16, 0, 0);
#pragma unroll
    for (int i = 0; i < 3; ++i) {
      __builtin_amdgcn_global_load_lds(
          (const __attribute__((address_space(1))) unsigned int*)(Bt + (size_t)nsrc[i] * K + k0 + aoff),
          (__attribute__((address_space(3))) unsigned int*)(Bs + i * 4096 + tid * 8), 16, 0, 0);
    }
    __syncthreads();
    short8 af[4], bfr[6];
#pragma unroll
    for (int i = 0; i < 4; ++i)
      af[i] = *(const short8*)&As[(wm + i * 16 + r16) * 32 + q * 8];
#pragma unroll
    for (int i = 0; i < 6; ++i)
      bfr[i] = *(const short8*)&Bs[(w2 * 96 + i * 16 + r16) * 32 + q * 8];
#pragma unroll
    for (int mi = 0; mi < 4; ++mi)
#pragma unroll
      for (int ni = 0; ni < 6; ++ni)
        acc[mi][ni] = __builtin_amdgcn_mfma_f32_16x16x32_bf16(af[mi], bfr[ni], acc[mi][ni], 0, 0, 0);
    __syncthreads();
  }

  // epilogue: C/D layout col=lane&15, row=(lane>>4)*4+reg (verified m89/m91)
  // frag ni: plane p = ni%3, dcol = dc0 + w2*32 + (ni/3)*16 + r16
#pragma unroll
  for (int mi = 0; mi < 4; ++mi)
#pragma unroll
    for (int half = 0; half < 2; ++half) {
      int dcol = dc0 + w2 * 32 + half * 16 + r16;
#pragma unroll
      for (int i = 0; i < 4; ++i) {
        int m = m0 + wm + mi * 16 + q * 4 + i;
        size_t rec = (size_t)m * D + dcol;
        unsigned x = A[rec];
        unsigned ua = (unsigned)f2bf(acc[mi][half * 3 + 0][i]) |
                      ((unsigned)f2bf(acc[mi][half * 3 + 1][i]) << 16);
        unsigned ub = (unsigned)f2bf(acc[mi][half * 3 + 2][i]) | (x << 16);
        Ua32[rec] = ua;
        Ub32[rec] = ub;
      }
    }
}

// ---- Kernel A: serial c-chain, register-double-buffered global loads.
// 64 blocks x 64 threads (1 wave/block). Minimum per-step work only; h is
// done by the parallel hpost kernel (R2 fusion experiment proved the serial
// wave must not carry the h trans ops).
__global__ __launch_bounds__(64) void cchain_kernel(unsigned* __restrict__ Uac,
                                                    const float* __restrict__ vsl,
                                                    const float* __restrict__ bsl,
                                                    const int* __restrict__ lenb) {
  int tid = threadIdx.x;
  int ch = blockIdx.x * 64 + tid;
  int b = ch >> 9;              // uniform per block
  int d = ch & 511;
  int len = lenb[b];
  const float NL2E = -1.4426950408889634f;
  float vfe = NL2E * vsl[d];
  float cbf = NL2E * bsl[d];
  const unsigned* pa = Uac + ch;
  float* pc = (float*)Uac + ch;
  int nact = (len + 31) >> 5;   // 32..64 chunks of 32 steps

  unsigned uA[32], uB[32];

#define CLOAD(k, u)                                         \
  _Pragma("unroll") for (int j = 0; j < 32; ++j)            \
      u[j] = pa[(size_t)((k) * 32 + j) * REC];

#define CCOMP(k, u)                                         \
  _Pragma("unroll") for (int j = 0; j < 32; ++j) {          \
    unsigned a = u[j];                                      \
    float u0 = __builtin_bit_cast(float, a << 16);          \
    float u1f = __builtin_bit_cast(float, a & 0xFFFF0000u); \
    float k1 = fmaf(u1f, NL2E, cbf);                        \
    float a2 = fmaf(vfe, c, k1);                            \
    float e = EXP2F(a2);                                    \
    float inv = RCPF(e + 1.f);                              \
    c = fmaf(c - u0, inv, u0);                              \
    pc[(size_t)((k) * 32 + j) * REC] = c;                   \
  }

  CLOAD(0, uA);
  float c = 0.f;
  int k = 0;
  for (;;) {
    if (k + 1 < nact) CLOAD(k + 1, uB);
    CCOMP(k, uA);
    if (++k >= nact) break;
    if (k + 1 < nact) CLOAD(k + 1, uA);
    CCOMP(k, uB);
    if (++k >= nact) break;
  }
#undef CLOAD
#undef CCOMP
  // t >= nact*32: c region stale; hpost masks h=0 there, never reads stale c into output.
}

// ---- Kernel B: parallel h epilogue. h_t = r*tanh(c_t) + (1-r)*x, r = sigm(u2+vr*c_{t-1}+br).
template <bool LAST>
__global__ __launch_bounds__(256) void hpost_kernel(const uint4* __restrict__ Ubq,
                                                    const float4* __restrict__ cq,
                                                    const float* __restrict__ vsl,
                                                    const float* __restrict__ bsl,
                                                    const int* __restrict__ lenb,
                                                    unsigned short* __restrict__ Hout,
                                                    float* __restrict__ Out) {
  int idx = blockIdx.x * 256 + threadIdx.x;   // = t*1024 + q
  int t = idx >> 10;
  int q = idx & 1023;
  int rec0 = q << 2;
  int b = rec0 >> 9;
  int d = rec0 & 511;
  int len = lenb[b];
  uint4 w = Ubq[idx];
  float4 ct = cq[idx];
  float4 cp = (t > 0) ? cq[idx - 1024] : make_float4(0.f, 0.f, 0.f, 0.f);
  float4 vr4 = *(const float4*)(vsl + D + d);
  float4 br4 = *(const float4*)(bsl + D + d);
  const float NL2E = -1.4426950408889634f;
  const float L2E2 = 2.8853900817779268f;
  unsigned ww[4] = {w.x, w.y, w.z, w.w};
  float cta[4] = {ct.x, ct.y, ct.z, ct.w};
  float cpa[4] = {cp.x, cp.y, cp.z, cp.w};
  float vra[4] = {vr4.x, vr4.y, vr4.z, vr4.w};
  float bra[4] = {br4.x, br4.y, br4.z, br4.w};
  bool act = t < len;
  float h[4];
#pragma unroll
  for (int j = 0; j < 4; ++j) {
    float u2 = __builtin_bit_cast(float, ww[j] << 16);
    float xf = __builtin_bit_cast(float, ww[j] & 0xFFFF0000u);
    float k2 = fmaf(u2, NL2E, NL2E * bra[j]);
    float a2 = fmaf(NL2E * vra[j], cpa[j], k2);
    float r = RCPF(EXP2F(a2) + 1.f);
    float et = EXP2F(cta[j] * L2E2);
    float th = fmaf(-2.f, RCPF(et + 1.f), 1.f);
    float hv = fmaf(r, th - xf, xf);
    h[j] = act ? hv : 0.f;
  }
  if (LAST) {
    *(float4*)(Out + ((size_t)b * TT + t) * D + d) = make_float4(h[0], h[1], h[2], h[3]);
  } else {
    ushort4 o; o.x = f2bf(h[0]); o.y = f2bf(h[1]); o.z = f2bf(h[2]); o.w = f2bf(h[3]);
    *(ushort4*)(Hout + (size_t)idx * 4) = o;    // (t*8+b)*512+d == idx*4
  }
}

extern "C" void kernel_launch(void* const* d_in, const int* in_sizes, int n_in,
                              void* d_out, int out_size, void* d_ws, size_t ws_size,
                              hipStream_t stream) {
  const int* ids = (const int*)d_in[0];
  const void* mask = d_in[1];
  const float* emb = (const float*)d_in[2];
  const float* Ws = (const float*)d_in[3];
  const float* vs = (const float*)d_in[4];
  const float* bs = (const float*)d_in[5];
  float* out = (float*)d_out;

  char* ws = (char*)d_ws;
  unsigned short* Ua = (unsigned short*)ws;                   // 33.5 MB (u0|u1 per rec; later holds c as f32)
  unsigned short* Ub = Ua + (size_t)TT * REC * 2;             // 33.5 MB (u2|x per rec)
  unsigned short* xa = Ub + (size_t)TT * REC * 2;             // 16.8 MB
  unsigned short* xb = xa + (size_t)TT * BATCH * D;           // 16.8 MB
  unsigned short* Wt = xb + (size_t)TT * BATCH * D;           // 3.1 MB
  int* lenb = (int*)(Wt + (size_t)L_LAYERS * D * N3);

  embed_kernel<<<BATCH * TT, 128, 0, stream>>>(ids, emb, xa);
  wconv_kernel<<<(L_LAYERS * D * N3 + 255) / 256, 256, 0, stream>>>(Ws, Wt);
  len_kernel<<<1, 64, 0, stream>>>(mask, lenb);

  // layer 0
  gemm_kernel<<<512, 512, 0, stream>>>(xa, Wt, (unsigned*)Ua, (unsigned*)Ub);
  cchain_kernel<<<64, 64, 0, stream>>>((unsigned*)Ua, vs, bs, lenb);
  hpost_kernel<false><<<8192, 256, 0, stream>>>((const uint4*)Ub, (const float4*)Ua,
                                                vs, bs, lenb, xb, nullptr);
  // layer 1
  gemm_kernel<<<512, 512, 0, stream>>>(xb, Wt + (size_t)N3 * D, (unsigned*)Ua, (unsigned*)Ub);
  cchain_kernel<<<64, 64, 0, stream>>>((unsigned*)Ua, vs + 2 * D, bs + 2 * D, lenb);
  hpost_kernel<true><<<8192, 256, 0, stream>>>((const uint4*)Ub, (const float4*)Ua,
                                               vs + 2 * D, bs + 2 * D, lenb, nullptr, out);
}

// Round 4
// 473.957 us; speedup vs baseline: 1.4368x; 1.0226x over previous
//
#include <hip/hip_runtime.h>
#include <hip/hip_bf16.h>

#define D 512
#define L_LAYERS 2
#define BATCH 8
#define TT 2048
#define N3 1536   // 3*D
#define REC 4096  // BATCH*D

typedef __attribute__((ext_vector_type(8))) short short8;
typedef __attribute__((ext_vector_type(4))) float floatx4;

#if __has_builtin(__builtin_amdgcn_exp2f)
#define EXP2F(x) __builtin_amdgcn_exp2f(x)
#else
#define EXP2F(x) exp2f(x)
#endif
#if __has_builtin(__builtin_amdgcn_rcpf)
#define RCPF(x) __builtin_amdgcn_rcpf(x)
#else
#define RCPF(x) (1.0f / (x))
#endif

__device__ __forceinline__ unsigned short f2bf(float f) {
  unsigned u = __builtin_bit_cast(unsigned, f);
  u += 0x7FFFu + ((u >> 16) & 1u);
  return (unsigned short)(u >> 16);
}

// ---- embedding gather: xa[(t*B+b)*D + d] = bf16(emb[ids[b][t]][d])
__global__ __launch_bounds__(128) void embed_kernel(const int* __restrict__ ids,
                                                    const float* __restrict__ emb,
                                                    unsigned short* __restrict__ xa) {
  int bt = blockIdx.x;          // b*T + t
  int b = bt >> 11;
  int t = bt & 2047;
  int id = ids[bt];
  int d = threadIdx.x << 2;
  const float4 v = *(const float4*)(emb + (size_t)id * D + d);
  ushort4 w;
  w.x = f2bf(v.x); w.y = f2bf(v.y); w.z = f2bf(v.z); w.w = f2bf(v.w);
  *(ushort4*)(xa + ((size_t)t * BATCH + b) * D + d) = w;
}

// ---- W transpose + convert: Wt[l][n][k] = bf16(Ws[l][k][n]).
// Block 0, threads 248..255 also compute per-batch valid length (mask is
// monotone) -- fused here to save one kernel launch.
__global__ __launch_bounds__(256) void wconv_kernel(const float* __restrict__ Ws,
                                                    unsigned short* __restrict__ Wt,
                                                    const void* __restrict__ maskp,
                                                    int* __restrict__ lenb) {
  if (blockIdx.x == 0 && threadIdx.x >= 248) {
    int b = threadIdx.x - 248;
    int w0 = *(const int*)maskp;
    int mode = (w0 == 1) ? 0 : ((w0 == 0x01010101) ? 1 : 2);  // i32 / u8 / f32
    int lo = 0, hi = TT;
    while (lo < hi) {
      int mid = (lo + hi) >> 1;
      int idx = b * TT + mid;
      bool mm = (mode == 0) ? (((const int*)maskp)[idx] != 0)
              : (mode == 1) ? (((const unsigned char*)maskp)[idx] != 0)
                            : (((const float*)maskp)[idx] != 0.f);
      if (mm) lo = mid + 1; else hi = mid;
    }
    lenb[b] = lo;
  }
  int idx = blockIdx.x * 256 + threadIdx.x;
  if (idx >= L_LAYERS * D * N3) return;
  int n = idx % N3;
  int k = (idx / N3) % D;
  int l = idx / (N3 * D);
  Wt[((size_t)l * N3 + n) * D + k] = f2bf(Ws[idx]);
}

// ---- 3-plane NT bf16 MFMA GEMM. One block computes a 128(m) x 128(dcol)
// output patch for ALL THREE planes (n = dcol, dcol+512, dcol+1024):
//   Ua[rec] u32 = u0 | u1<<16,  Uc[rec] u16 = u2   (rec = m*512+dcol, m=t*8+b)
// (x is NOT packed through the GEMM anymore -- hpost reads it from xa/xb
//  directly, killing the epilogue's 2-byte A-gather and halving the u2 write.)
// Bs columns interleaved per-16 (plane p = (c>>4)%3) so a wave's 96-col slice
// contains all 3 planes of its 32 dcols. 512 threads / 8 waves: wave covers
// 64 m x 96 c -> acc[4][6]. XCD swizzle: 4 dcol-blocks of same bm share the
// A-panel in L2.
__global__ __launch_bounds__(512) void gemm_kernel(const unsigned short* __restrict__ A,
                                                   const unsigned short* __restrict__ Bt,
                                                   unsigned* __restrict__ Ua32,
                                                   unsigned short* __restrict__ Uc16) {
  constexpr int K = D;
  __shared__ __align__(16) unsigned short As[128 * 32];   // 8 KB
  __shared__ __align__(16) unsigned short Bs[384 * 32];   // 24 KB
  int tid = threadIdx.x;
  int lane = tid & 63;
  int wave = tid >> 6;           // 0..7
  int bi = blockIdx.x;
  int xcd = bi & 7;
  int j = bi >> 3;               // 0..63
  int bm = xcd * 16 + (j >> 2);  // 0..127
  int dc0 = (j & 3) * 128;
  int m0 = bm * 128;
  int wm = (wave & 1) * 64;
  int w2 = wave >> 1;            // 0..3
  int q = lane >> 4, r16 = lane & 15;

  // staging geometry: each thread stages one 16B slot per tile
  int arow = tid >> 2;           // 0..127
  int aoff = (tid & 3) * 8;      // ushort offset within 32-col row
  int nsrc[3];
#pragma unroll
  for (int i = 0; i < 3; ++i) {
    int c = arow + i * 128;      // Bs column 0..383
    int g = c >> 4;              // 0..23
    int p = g % 3;
    int dcol = (g / 3) * 16 + (c & 15);
    nsrc[i] = dc0 + dcol + p * 512;
  }
  const unsigned short* asrc = A + (size_t)(m0 + arow) * K + aoff;

  floatx4 acc[4][6] = {};

  for (int k0 = 0; k0 < K; k0 += 32) {
    __builtin_amdgcn_global_load_lds(
        (const __attribute__((address_space(1))) unsigned int*)(asrc + k0),
        (__attribute__((address_space(3))) unsigned int*)(As + tid * 8), 16, 0, 0);
#pragma unroll
    for (int i = 0; i < 3; ++i) {
      __builtin_amdgcn_global_load_lds(
          (const __attribute__((address_space(1))) unsigned int*)(Bt + (size_t)nsrc[i] * K + k0 + aoff),
          (__attribute__((address_space(3))) unsigned int*)(Bs + i * 4096 + tid * 8), 16, 0, 0);
    }
    __syncthreads();
    short8 af[4], bfr[6];
#pragma unroll
    for (int i = 0; i < 4; ++i)
      af[i] = *(const short8*)&As[(wm + i * 16 + r16) * 32 + q * 8];
#pragma unroll
    for (int i = 0; i < 6; ++i)
      bfr[i] = *(const short8*)&Bs[(w2 * 96 + i * 16 + r16) * 32 + q * 8];
#pragma unroll
    for (int mi = 0; mi < 4; ++mi)
#pragma unroll
      for (int ni = 0; ni < 6; ++ni)
        acc[mi][ni] = __builtin_amdgcn_mfma_f32_16x16x32_bf16(af[mi], bfr[ni], acc[mi][ni], 0, 0, 0);
    __syncthreads();
  }

  // epilogue: C/D layout col=lane&15, row=(lane>>4)*4+reg (verified m89/m91)
  // frag ni: plane p = ni%3, dcol = dc0 + w2*32 + (ni/3)*16 + r16
#pragma unroll
  for (int mi = 0; mi < 4; ++mi)
#pragma unroll
    for (int half = 0; half < 2; ++half) {
      int dcol = dc0 + w2 * 32 + half * 16 + r16;
#pragma unroll
      for (int i = 0; i < 4; ++i) {
        int m = m0 + wm + mi * 16 + q * 4 + i;
        size_t rec = (size_t)m * D + dcol;
        unsigned ua = (unsigned)f2bf(acc[mi][half * 3 + 0][i]) |
                      ((unsigned)f2bf(acc[mi][half * 3 + 1][i]) << 16);
        Ua32[rec] = ua;
        Uc16[rec] = f2bf(acc[mi][half * 3 + 2][i]);
      }
    }
}

// ---- Kernel A: serial c-chain, register-double-buffered global loads.
// 64 blocks x 64 threads (1 wave/block). Minimum per-step work only; h is
// done by the parallel hpost kernel (R2 fusion experiment proved the serial
// wave must not carry the h trans ops). ~93.3 us, near the dep-chain floor
// (fma->exp->add->rcp->fma ~= 92 cyc/step).
__global__ __launch_bounds__(64) void cchain_kernel(unsigned* __restrict__ Uac,
                                                    const float* __restrict__ vsl,
                                                    const float* __restrict__ bsl,
                                                    const int* __restrict__ lenb) {
  int tid = threadIdx.x;
  int ch = blockIdx.x * 64 + tid;
  int b = ch >> 9;              // uniform per block
  int d = ch & 511;
  int len = lenb[b];
  const float NL2E = -1.4426950408889634f;
  float vfe = NL2E * vsl[d];
  float cbf = NL2E * bsl[d];
  const unsigned* pa = Uac + ch;
  float* pc = (float*)Uac + ch;
  int nact = (len + 31) >> 5;   // 32..64 chunks of 32 steps

  unsigned uA[32], uB[32];

#define CLOAD(k, u)                                         \
  _Pragma("unroll") for (int j = 0; j < 32; ++j)            \
      u[j] = pa[(size_t)((k) * 32 + j) * REC];

#define CCOMP(k, u)                                         \
  _Pragma("unroll") for (int j = 0; j < 32; ++j) {          \
    unsigned a = u[j];                                      \
    float u0 = __builtin_bit_cast(float, a << 16);          \
    float u1f = __builtin_bit_cast(float, a & 0xFFFF0000u); \
    float k1 = fmaf(u1f, NL2E, cbf);                        \
    float a2 = fmaf(vfe, c, k1);                            \
    float e = EXP2F(a2);                                    \
    float inv = RCPF(e + 1.f);                              \
    c = fmaf(c - u0, inv, u0);                              \
    pc[(size_t)((k) * 32 + j) * REC] = c;                   \
  }

  CLOAD(0, uA);
  float c = 0.f;
  int k = 0;
  for (;;) {
    if (k + 1 < nact) CLOAD(k + 1, uB);
    CCOMP(k, uA);
    if (++k >= nact) break;
    if (k + 1 < nact) CLOAD(k + 1, uA);
    CCOMP(k, uB);
    if (++k >= nact) break;
  }
#undef CLOAD
#undef CCOMP
  // t >= nact*32: c region stale; hpost masks h=0 there, never reads stale c into output.
}

// ---- Kernel B: parallel h epilogue. h_t = r*tanh(c_t) + (1-r)*x, r = sigm(u2+vr*c_{t-1}+br).
// u2 from Uc (ushort plane), x from the layer input xa/xb (same rec layout).
template <bool LAST>
__global__ __launch_bounds__(256) void hpost_kernel(const unsigned short* __restrict__ Uc,
                                                    const unsigned short* __restrict__ Xin,
                                                    const float4* __restrict__ cq,
                                                    const float* __restrict__ vsl,
                                                    const float* __restrict__ bsl,
                                                    const int* __restrict__ lenb,
                                                    unsigned short* __restrict__ Hout,
                                                    float* __restrict__ Out) {
  int idx = blockIdx.x * 256 + threadIdx.x;   // = t*1024 + q
  int t = idx >> 10;
  int q = idx & 1023;
  int rec0 = q << 2;
  int b = rec0 >> 9;
  int d = rec0 & 511;
  int len = lenb[b];
  ushort4 uv = *(const ushort4*)(Uc + (size_t)idx * 4);
  ushort4 xv = *(const ushort4*)(Xin + (size_t)idx * 4);
  float4 ct = cq[idx];
  float4 cp = (t > 0) ? cq[idx - 1024] : make_float4(0.f, 0.f, 0.f, 0.f);
  float4 vr4 = *(const float4*)(vsl + D + d);
  float4 br4 = *(const float4*)(bsl + D + d);
  const float NL2E = -1.4426950408889634f;
  const float L2E2 = 2.8853900817779268f;
  unsigned uu[4] = {uv.x, uv.y, uv.z, uv.w};
  unsigned xx[4] = {xv.x, xv.y, xv.z, xv.w};
  float cta[4] = {ct.x, ct.y, ct.z, ct.w};
  float cpa[4] = {cp.x, cp.y, cp.z, cp.w};
  float vra[4] = {vr4.x, vr4.y, vr4.z, vr4.w};
  float bra[4] = {br4.x, br4.y, br4.z, br4.w};
  bool act = t < len;
  float h[4];
#pragma unroll
  for (int j = 0; j < 4; ++j) {
    float u2 = __builtin_bit_cast(float, uu[j] << 16);
    float xf = __builtin_bit_cast(float, xx[j] << 16);
    float k2 = fmaf(u2, NL2E, NL2E * bra[j]);
    float a2 = fmaf(NL2E * vra[j], cpa[j], k2);
    float r = RCPF(EXP2F(a2) + 1.f);
    float et = EXP2F(cta[j] * L2E2);
    float th = fmaf(-2.f, RCPF(et + 1.f), 1.f);
    float hv = fmaf(r, th - xf, xf);
    h[j] = act ? hv : 0.f;
  }
  if (LAST) {
    *(float4*)(Out + ((size_t)b * TT + t) * D + d) = make_float4(h[0], h[1], h[2], h[3]);
  } else {
    ushort4 o; o.x = f2bf(h[0]); o.y = f2bf(h[1]); o.z = f2bf(h[2]); o.w = f2bf(h[3]);
    *(ushort4*)(Hout + (size_t)idx * 4) = o;    // (t*8+b)*512+d == idx*4
  }
}

extern "C" void kernel_launch(void* const* d_in, const int* in_sizes, int n_in,
                              void* d_out, int out_size, void* d_ws, size_t ws_size,
                              hipStream_t stream) {
  const int* ids = (const int*)d_in[0];
  const void* mask = d_in[1];
  const float* emb = (const float*)d_in[2];
  const float* Ws = (const float*)d_in[3];
  const float* vs = (const float*)d_in[4];
  const float* bs = (const float*)d_in[5];
  float* out = (float*)d_out;

  char* ws = (char*)d_ws;
  unsigned short* Ua = (unsigned short*)ws;                   // 33.5 MB dword/rec (u0|u1; later c as f32)
  unsigned short* Uc = Ua + (size_t)TT * REC * 2;             // 16.8 MB ushort/rec (u2)
  unsigned short* xa = Uc + (size_t)TT * REC;                 // 16.8 MB
  unsigned short* xb = xa + (size_t)TT * REC;                 // 16.8 MB
  unsigned short* Wt = xb + (size_t)TT * REC;                 // 3.1 MB
  int* lenb = (int*)(Wt + (size_t)L_LAYERS * D * N3);

  embed_kernel<<<BATCH * TT, 128, 0, stream>>>(ids, emb, xa);
  wconv_kernel<<<(L_LAYERS * D * N3 + 255) / 256, 256, 0, stream>>>(Ws, Wt, mask, lenb);

  // layer 0
  gemm_kernel<<<512, 512, 0, stream>>>(xa, Wt, (unsigned*)Ua, Uc);
  cchain_kernel<<<64, 64, 0, stream>>>((unsigned*)Ua, vs, bs, lenb);
  hpost_kernel<false><<<8192, 256, 0, stream>>>(Uc, xa, (const float4*)Ua,
                                                vs, bs, lenb, xb, nullptr);
  // layer 1
  gemm_kernel<<<512, 512, 0, stream>>>(xb, Wt + (size_t)N3 * D, (unsigned*)Ua, Uc);
  cchain_kernel<<<64, 64, 0, stream>>>((unsigned*)Ua, vs + 2 * D, bs + 2 * D, lenb);
  hpost_kernel<true><<<8192, 256, 0, stream>>>(Uc, xb, (const float4*)Ua,
                                               vs + 2 * D, bs + 2 * D, lenb, nullptr, out);
}